// Round 1
// 823.592 us; speedup vs baseline: 1.0584x; 1.0584x over previous
//
#include <hip/hip_runtime.h>

// deltaLayer: out[b,c,i,j] = |l[b,c,j] - r[b,c,i]|
// BS=2, CHAN=128, H=1, W=900 -> out is (2,128,900,900) fp32 = 829.4 MB.
// Pure write-BW bound. l/r rows staged in LDS; coalesced nontemporal
// float4 stores.
//
// R1: parallelism + ILP push. Previous version: 1024 blocks (16 waves/CU),
// runtime-trip-count loop -> one dependent ds_read chain in flight per
// wave, ~2.4 TB/s effective write BW. This version:
//   - SPLIT 4 -> 16 (4096 blocks), __launch_bounds__(256,8) -> 32 waves/CU
//   - PART = 50*256 so full parts run a compile-time 50-iteration loop,
//     #pragma unroll 5 -> 5 independent ds_read/store chains per wave.

#define BS    2
#define CHAN  128
#define W     900
#define W4    225                // W/4 float4 per output row
#define TILE4 (W * W4)           // 202500 float4 per (b,c) tile
#define SPLIT 16                 // blocks per (b,c) tile
#define PART  12800              // 50*256 float4 per full part
#define NFULL 50                 // iterations/thread in full parts

typedef float v4f __attribute__((ext_vector_type(4)));

__global__ __launch_bounds__(256, 8)
void deltaLayer_57294863728910_kernel(const float* __restrict__ l,
                                      const float* __restrict__ r,
                                      float* __restrict__ out) {
    __shared__ float sl[W];
    __shared__ float sr[W];

    const int bc   = blockIdx.x >> 4;          // (b*CHAN + c), 0..255
    const int part = blockIdx.x & (SPLIT - 1); // 0..15

    const float* lrow = l + bc * W;
    const float* rrow = r + bc * W;
    for (int t = threadIdx.x; t < W; t += 256) {
        sl[t] = lrow[t];
        sr[t] = rrow[t];
    }
    __syncthreads();

    v4f* out4 = (v4f*)out + (size_t)bc * TILE4;
    const int kbeg = part * PART;

    if (part != SPLIT - 1) {
        // full part: exactly NFULL iterations for every thread
        int k = kbeg + (int)threadIdx.x;
        #pragma unroll 5
        for (int n = 0; n < NFULL; ++n, k += 256) {
            int i  = k / W4;                 // magic-multiply, no HW div
            int j4 = k - i * W4;
            float rv = sr[i];
            v4f   lv = *(const v4f*)&sl[j4 * 4];
            v4f   o;
            o.x = fabsf(lv.x - rv);
            o.y = fabsf(lv.y - rv);
            o.z = fabsf(lv.z - rv);
            o.w = fabsf(lv.w - rv);
            __builtin_nontemporal_store(o, &out4[k]);
        }
    } else {
        // tail part: 202500 - 15*12800 = 10500 float4
        for (int k = kbeg + (int)threadIdx.x; k < TILE4; k += 256) {
            int i  = k / W4;
            int j4 = k - i * W4;
            float rv = sr[i];
            v4f   lv = *(const v4f*)&sl[j4 * 4];
            v4f   o;
            o.x = fabsf(lv.x - rv);
            o.y = fabsf(lv.y - rv);
            o.z = fabsf(lv.z - rv);
            o.w = fabsf(lv.w - rv);
            __builtin_nontemporal_store(o, &out4[k]);
        }
    }
}

extern "C" void kernel_launch(void* const* d_in, const int* in_sizes, int n_in,
                              void* d_out, int out_size, void* d_ws, size_t ws_size,
                              hipStream_t stream) {
    const float* l = (const float*)d_in[0];
    const float* r = (const float*)d_in[1];
    float* out = (float*)d_out;

    dim3 grid(BS * CHAN * SPLIT);   // 4096 blocks
    dim3 block(256);
    deltaLayer_57294863728910_kernel<<<grid, block, 0, stream>>>(l, r, out);
}

// Round 2
// 807.728 us; speedup vs baseline: 1.0792x; 1.0196x over previous
//
#include <hip/hip_runtime.h>

// deltaLayer: out[b,c,i,j] = |l[b,c,j] - r[b,c,i]|
// BS=2, CHAN=128, H=1, W=900 -> out is (2,128,900,900) fp32 = 829.4 MB.
// Pure write-BW bound. l/r rows staged in LDS; coalesced float4 stores.
//
// R1: SPLIT 16 (4096 blocks), 32 waves/CU, unroll-5 -> only +15%.
//     => not latency/occupancy-bound. Issue math: ~19 inst/KB-wave vs
//     12x issue headroom => not VALU-bound either.
// R2: single-variable test of the store path. The harness's own
//     fillBufferAligned hits 6.29 TB/s on this same buffer with plain
//     stores; our only difference was __builtin_nontemporal_store
//     (nt = no-allocate hint; suspected partial-line write traffic or
//     split into 4x dword stores). Replace with plain float4 store ->
//     guaranteed global_store_dwordx4 through the normal L2
//     write-combining path, mimicking the fill kernel exactly.

#define BS    2
#define CHAN  128
#define W     900
#define W4    225                // W/4 float4 per output row
#define TILE4 (W * W4)           // 202500 float4 per (b,c) tile
#define SPLIT 16                 // blocks per (b,c) tile
#define PART  12800              // 50*256 float4 per full part
#define NFULL 50                 // iterations/thread in full parts

typedef float v4f __attribute__((ext_vector_type(4)));

__global__ __launch_bounds__(256, 8)
void deltaLayer_57294863728910_kernel(const float* __restrict__ l,
                                      const float* __restrict__ r,
                                      float* __restrict__ out) {
    __shared__ float sl[W];
    __shared__ float sr[W];

    const int bc   = blockIdx.x >> 4;          // (b*CHAN + c), 0..255
    const int part = blockIdx.x & (SPLIT - 1); // 0..15

    const float* lrow = l + bc * W;
    const float* rrow = r + bc * W;
    for (int t = threadIdx.x; t < W; t += 256) {
        sl[t] = lrow[t];
        sr[t] = rrow[t];
    }
    __syncthreads();

    v4f* out4 = (v4f*)out + (size_t)bc * TILE4;
    const int kbeg = part * PART;

    if (part != SPLIT - 1) {
        // full part: exactly NFULL iterations for every thread
        int k = kbeg + (int)threadIdx.x;
        #pragma unroll 5
        for (int n = 0; n < NFULL; ++n, k += 256) {
            int i  = k / W4;                 // magic-multiply, no HW div
            int j4 = k - i * W4;
            float rv = sr[i];
            v4f   lv = *(const v4f*)&sl[j4 * 4];
            v4f   o;
            o.x = fabsf(lv.x - rv);
            o.y = fabsf(lv.y - rv);
            o.z = fabsf(lv.z - rv);
            o.w = fabsf(lv.w - rv);
            out4[k] = o;                     // plain global_store_dwordx4
        }
    } else {
        // tail part: 202500 - 15*12800 = 10500 float4
        for (int k = kbeg + (int)threadIdx.x; k < TILE4; k += 256) {
            int i  = k / W4;
            int j4 = k - i * W4;
            float rv = sr[i];
            v4f   lv = *(const v4f*)&sl[j4 * 4];
            v4f   o;
            o.x = fabsf(lv.x - rv);
            o.y = fabsf(lv.y - rv);
            o.z = fabsf(lv.z - rv);
            o.w = fabsf(lv.w - rv);
            out4[k] = o;
        }
    }
}

extern "C" void kernel_launch(void* const* d_in, const int* in_sizes, int n_in,
                              void* d_out, int out_size, void* d_ws, size_t ws_size,
                              hipStream_t stream) {
    const float* l = (const float*)d_in[0];
    const float* r = (const float*)d_in[1];
    float* out = (float*)d_out;

    dim3 grid(BS * CHAN * SPLIT);   // 4096 blocks
    dim3 block(256);
    deltaLayer_57294863728910_kernel<<<grid, block, 0, stream>>>(l, r, out);
}